// Round 1
// baseline (1577.781 us; speedup 1.0000x reference)
//
#include <hip/hip_runtime.h>
#include <cstdio>

#define Nn 50000
#define Ee 800000
#define Ff 512
#define Dd 256
#define Gg 8

// ---------------- CSR build ----------------

__global__ void hist_kernel(const int* __restrict__ dst, int* __restrict__ deg) {
  int i = blockIdx.x * blockDim.x + threadIdx.x;
  int stride = gridDim.x * blockDim.x;
  for (; i < Ee; i += stride) atomicAdd(&deg[dst[i]], 1);
}

__global__ __launch_bounds__(1024) void scan_kernel(const int* __restrict__ deg, int* __restrict__ off) {
  __shared__ int wsum[16];
  __shared__ int carry;
  int tid = threadIdx.x;
  int lane = tid & 63, w = tid >> 6;
  if (tid == 0) carry = 0;
  __syncthreads();
  for (int start = 0; start < Nn; start += 1024) {
    int i = start + tid;
    int v = (i < Nn) ? deg[i] : 0;
    int x = v;
#pragma unroll
    for (int o = 1; o < 64; o <<= 1) {
      int t = __shfl_up(x, o);
      if (lane >= o) x += t;
    }
    if (lane == 63) wsum[w] = x;
    __syncthreads();
    if (w == 0 && lane < 16) {
      int y = wsum[lane];
#pragma unroll
      for (int o = 1; o < 16; o <<= 1) {
        int t = __shfl_up(y, o);
        if (lane >= o) y += t;
      }
      wsum[lane] = y;
    }
    __syncthreads();
    int cb = carry;
    int incl = x + (w ? wsum[w - 1] : 0);
    if (i < Nn) off[i] = cb + incl - v;
    __syncthreads();
    if (tid == 1023) carry = cb + incl;
    __syncthreads();
  }
  if (tid == 0) off[Nn] = carry;
}

__global__ void scatter_kernel(const int* __restrict__ src, const int* __restrict__ dst,
                               const int* __restrict__ off, int* __restrict__ cur,
                               int* __restrict__ ssrc) {
  int i = blockIdx.x * blockDim.x + threadIdx.x;
  int stride = gridDim.x * blockDim.x;
  for (; i < Ee; i += stride) {
    int d = dst[i];
    int pos = off[d] + atomicAdd(&cur[d], 1);
    ssrc[pos] = src[i];
  }
}

// ---------------- fp32 GEMM: out[z] = A @ Wz + bz, z in {q,k,v,s} ----------------

__global__ __launch_bounds__(256)
void gemm4_kernel(const float* __restrict__ A, int M, int K,
                  const float* __restrict__ W0, const float* __restrict__ W1,
                  const float* __restrict__ W2, const float* __restrict__ W3,
                  const float* __restrict__ b0, const float* __restrict__ b1,
                  const float* __restrict__ b2, const float* __restrict__ b3,
                  float* __restrict__ out) {
  constexpr int BM = 128, BN = 128, BK = 16, LDT = BM + 4;
  __shared__ float As[BK][LDT];
  __shared__ float Bs[BK][LDT];
  int tid = threadIdx.x;
  int bm = blockIdx.x * BM;
  int bn = blockIdx.y * BN;
  int z = blockIdx.z;
  const float* W  = (z == 0) ? W0 : (z == 1) ? W1 : (z == 2) ? W2 : W3;
  const float* bi = (z == 0) ? b0 : (z == 1) ? b1 : (z == 2) ? b2 : b3;
  float* C = out + (size_t)z * M * Dd;

  int ty = tid >> 4, tx = tid & 15;
  int arow = tid >> 2;
  int ak = (tid & 3) << 2;
  int brow = tid >> 5;
  int bc = (tid & 31) << 2;

  float acc[8][8] = {};

  for (int kk = 0; kk < K; kk += BK) {
#pragma unroll
    for (int half = 0; half < 2; ++half) {
      int r = arow + half * 64;
      int grow = bm + r;
      float4 av = make_float4(0.f, 0.f, 0.f, 0.f);
      if (grow < M) av = *(const float4*)(A + (size_t)grow * K + kk + ak);
      As[ak + 0][r] = av.x; As[ak + 1][r] = av.y;
      As[ak + 2][r] = av.z; As[ak + 3][r] = av.w;
    }
#pragma unroll
    for (int half = 0; half < 2; ++half) {
      int r = brow + half * 8;
      float4 bv = *(const float4*)(W + (size_t)(kk + r) * Dd + bn + bc);
      *(float4*)&Bs[r][bc] = bv;
    }
    __syncthreads();
#pragma unroll
    for (int k = 0; k < BK; ++k) {
      float a[8], b[8];
      *(float4*)&a[0] = *(const float4*)&As[k][ty * 8];
      *(float4*)&a[4] = *(const float4*)&As[k][ty * 8 + 4];
      *(float4*)&b[0] = *(const float4*)&Bs[k][tx * 8];
      *(float4*)&b[4] = *(const float4*)&Bs[k][tx * 8 + 4];
#pragma unroll
      for (int i = 0; i < 8; ++i)
#pragma unroll
        for (int j = 0; j < 8; ++j)
          acc[i][j] = fmaf(a[i], b[j], acc[i][j]);
    }
    __syncthreads();
  }
#pragma unroll
  for (int i = 0; i < 8; ++i) {
    int grow = bm + ty * 8 + i;
    if (grow < M) {
      float ov[8];
#pragma unroll
      for (int j = 0; j < 8; ++j) ov[j] = acc[i][j] + bi[bn + tx * 8 + j];
      *(float4*)(C + (size_t)grow * Dd + bn + tx * 8)     = *(float4*)&ov[0];
      *(float4*)(C + (size_t)grow * Dd + bn + tx * 8 + 4) = *(float4*)&ov[4];
    }
  }
}

// ---------------- per-node attention (one wave per dst node, online softmax) ----------------

__global__ __launch_bounds__(256)
void attn_kernel(const float* __restrict__ qkvs, const int* __restrict__ off,
                 const int* __restrict__ ssrc, float* __restrict__ hout) {
  int gw = (int)((blockIdx.x * 256 + threadIdx.x) >> 6);
  if (gw >= Nn) return;
  int lane = threadIdx.x & 63;
  const float* Kbase = qkvs + (size_t)Nn * Dd;
  const float* Vbase = Kbase + (size_t)Nn * Dd;
  const float* Sbase = Vbase + (size_t)Nn * Dd;

  float4 q = *(const float4*)(qkvs + (size_t)gw * Dd + lane * 4);
  int e0 = off[gw], e1 = off[gw + 1];
  const float scale = 0.08838834764831845f;

  float m = -3.4e38f, d = 0.f;
  float ax = 0.f, ay = 0.f, az = 0.f, aw = 0.f;

  for (int e = e0; e < e1; ++e) {
    int s = ssrc[e];
    float4 kv = *(const float4*)(Kbase + (size_t)s * Dd + lane * 4);
    float4 vv = *(const float4*)(Vbase + (size_t)s * Dd + lane * 4);
    float p = q.x * kv.x + q.y * kv.y + q.z * kv.z + q.w * kv.w;
    p += __shfl_xor(p, 16);
    p += __shfl_xor(p, 8);
    p += __shfl_xor(p, 4);
    p += __shfl_xor(p, 2);
    p += __shfl_xor(p, 1);
    float sc = p * scale;
    float nm = fmaxf(m, sc);
    float f = __expf(m - nm);
    float wgt = __expf(sc - nm);
    d = d * f + wgt;
    ax = ax * f + wgt * vv.x;
    ay = ay * f + wgt * vv.y;
    az = az * f + wgt * vv.z;
    aw = aw * f + wgt * vv.w;
    m = nm;
  }
  float inv = 1.f / (d + 1e-16f);
  float4 sk = *(const float4*)(Sbase + (size_t)gw * Dd + lane * 4);
  float4 o;
  o.x = fmaxf(ax * inv + sk.x, 0.f);
  o.y = fmaxf(ay * inv + sk.y, 0.f);
  o.z = fmaxf(az * inv + sk.z, 0.f);
  o.w = fmaxf(aw * inv + sk.w, 0.f);
  *(float4*)(hout + (size_t)gw * Dd + lane * 4) = o;
}

// ---------------- pooling + fc ----------------

__global__ __launch_bounds__(256)
void pool_kernel(const float* __restrict__ h, const int* __restrict__ batch,
                 float* __restrict__ pooled) {
  int c = threadIdx.x;
  int n0 = blockIdx.x * 128;
  int n1 = min(n0 + 128, Nn);
  int curg = batch[n0];
  float mx = 0.f;
  for (int n = n0; n < n1; ++n) {
    int g = batch[n];
    if (g != curg) {
      atomicMax((int*)(pooled + curg * Dd + c), __float_as_int(mx));
      mx = 0.f;
      curg = g;
    }
    mx = fmaxf(mx, h[(size_t)n * Dd + c]);
  }
  atomicMax((int*)(pooled + curg * Dd + c), __float_as_int(mx));
}

__global__ __launch_bounds__(512)
void fc_kernel(const float* __restrict__ pooled,
               const float* __restrict__ wf1, const float* __restrict__ bf1,
               const float* __restrict__ wf2, const float* __restrict__ bf2,
               float* __restrict__ outp) {
  __shared__ float t[Gg][64];
  int tid = threadIdx.x;
  int g = tid >> 6, j = tid & 63;
  float acc = bf1[j];
  for (int c = 0; c < Dd; ++c) acc = fmaf(pooled[g * Dd + c], wf1[c * 64 + j], acc);
  t[g][j] = acc;
  __syncthreads();
  if (tid < Gg * 4) {
    int gg = tid >> 2, cc = tid & 3;
    float a2 = bf2[cc];
    for (int j2 = 0; j2 < 64; ++j2) a2 = fmaf(t[gg][j2], wf2[j2 * 4 + cc], a2);
    outp[gg * 4 + cc] = a2;
  }
}

// ---------------- host ----------------

extern "C" void kernel_launch(void* const* d_in, const int* in_sizes, int n_in,
                              void* d_out, int out_size, void* d_ws, size_t ws_size,
                              hipStream_t stream) {
  const float* x   = (const float*)d_in[0];
  const int* ei    = (const int*)d_in[1];
  const int* srcE  = ei;
  const int* dstE  = ei + Ee;
  const int* batch = (const int*)d_in[2];
  const float* wq1 = (const float*)d_in[3];  const float* bq1 = (const float*)d_in[4];
  const float* wk1 = (const float*)d_in[5];  const float* bk1 = (const float*)d_in[6];
  const float* wv1 = (const float*)d_in[7];  const float* bv1 = (const float*)d_in[8];
  const float* ws1 = (const float*)d_in[9];  const float* bs1 = (const float*)d_in[10];
  const float* wq2 = (const float*)d_in[11]; const float* bq2 = (const float*)d_in[12];
  const float* wk2 = (const float*)d_in[13]; const float* bk2 = (const float*)d_in[14];
  const float* wv2 = (const float*)d_in[15]; const float* bv2 = (const float*)d_in[16];
  const float* ws2 = (const float*)d_in[17]; const float* bs2 = (const float*)d_in[18];
  const float* wf1 = (const float*)d_in[19]; const float* bf1 = (const float*)d_in[20];
  const float* wf2 = (const float*)d_in[21]; const float* bf2 = (const float*)d_in[22];
  float* outp = (float*)d_out;
  char* ws = (char*)d_ws;

  size_t o_deg  = 0;
  size_t o_cur  = o_deg + (size_t)Nn * 4;
  size_t o_pool = o_cur + (size_t)Nn * 4;
  size_t zbytes = o_pool + (size_t)Gg * Dd * 4;
  size_t o_off  = (zbytes + 255) & ~(size_t)255;
  size_t o_ssrc = (o_off + (size_t)(Nn + 1) * 4 + 255) & ~(size_t)255;
  size_t o_qkvs = (o_ssrc + (size_t)Ee * 4 + 255) & ~(size_t)255;
  size_t o_h    = o_qkvs + (size_t)4 * Nn * Dd * 4;
  size_t total  = o_h + (size_t)Nn * Dd * 4;
  if (ws_size < total) {
    fprintf(stderr, "kernel_launch: ws too small: %zu < %zu\n", ws_size, total);
    return;
  }

  int*   deg    = (int*)(ws + o_deg);
  int*   cur    = (int*)(ws + o_cur);
  float* pooled = (float*)(ws + o_pool);
  int*   off    = (int*)(ws + o_off);
  int*   ssrc   = (int*)(ws + o_ssrc);
  float* qkvs   = (float*)(ws + o_qkvs);
  float* h      = (float*)(ws + o_h);

  hipMemsetAsync(ws, 0, zbytes, stream);
  hist_kernel<<<1024, 256, 0, stream>>>(dstE, deg);
  scan_kernel<<<1, 1024, 0, stream>>>(deg, off);
  scatter_kernel<<<1024, 256, 0, stream>>>(srcE, dstE, off, cur, ssrc);

  dim3 ggrid((Nn + 127) / 128, Dd / 128, 4);
  gemm4_kernel<<<ggrid, 256, 0, stream>>>(x, Nn, Ff, wq1, wk1, wv1, ws1, bq1, bk1, bv1, bs1, qkvs);
  attn_kernel<<<(Nn + 3) / 4, 256, 0, stream>>>(qkvs, off, ssrc, h);
  gemm4_kernel<<<ggrid, 256, 0, stream>>>(h, Nn, Dd, wq2, wk2, wv2, ws2, bq2, bk2, bv2, bs2, qkvs);
  attn_kernel<<<(Nn + 3) / 4, 256, 0, stream>>>(qkvs, off, ssrc, h);
  pool_kernel<<<(Nn + 127) / 128, 256, 0, stream>>>(h, batch, pooled);
  fc_kernel<<<1, 512, 0, stream>>>(pooled, wf1, bf1, wf2, bf2, outp);
}

// Round 2
// 1104.530 us; speedup vs baseline: 1.4285x; 1.4285x over previous
//
#include <hip/hip_runtime.h>
#include <cstdio>

#define Nn 50000
#define Ee 800000
#define Ff 512
#define Dd 256
#define Gg 8

typedef short short8 __attribute__((ext_vector_type(8)));
typedef __bf16 bf16x8 __attribute__((ext_vector_type(8)));
typedef float f32x4 __attribute__((ext_vector_type(4)));

__device__ inline unsigned short f2bf(float f) {
  unsigned u = __float_as_uint(f);
  u += 0x7FFFu + ((u >> 16) & 1u);
  return (unsigned short)(u >> 16);
}
__device__ inline float bf2f(unsigned short h) {
  return __uint_as_float(((unsigned)h) << 16);
}

__device__ inline void gload16(const void* g, void* l) {
  __builtin_amdgcn_global_load_lds((const __attribute__((address_space(1))) void*)g,
                                   (__attribute__((address_space(3))) void*)l, 16, 0, 0);
}

// ---------------- CSR build ----------------

__global__ void hist_kernel(const int* __restrict__ dst, int* __restrict__ deg) {
  int i = blockIdx.x * blockDim.x + threadIdx.x;
  int stride = gridDim.x * blockDim.x;
  for (; i < Ee; i += stride) atomicAdd(&deg[dst[i]], 1);
}

__global__ __launch_bounds__(1024) void scan_kernel(const int* __restrict__ deg, int* __restrict__ off) {
  __shared__ int wsum[16];
  __shared__ int carry;
  int tid = threadIdx.x;
  int lane = tid & 63, w = tid >> 6;
  if (tid == 0) carry = 0;
  __syncthreads();
  for (int start = 0; start < Nn; start += 1024) {
    int i = start + tid;
    int v = (i < Nn) ? deg[i] : 0;
    int x = v;
#pragma unroll
    for (int o = 1; o < 64; o <<= 1) {
      int t = __shfl_up(x, o);
      if (lane >= o) x += t;
    }
    if (lane == 63) wsum[w] = x;
    __syncthreads();
    if (w == 0 && lane < 16) {
      int y = wsum[lane];
#pragma unroll
      for (int o = 1; o < 16; o <<= 1) {
        int t = __shfl_up(y, o);
        if (lane >= o) y += t;
      }
      wsum[lane] = y;
    }
    __syncthreads();
    int cb = carry;
    int incl = x + (w ? wsum[w - 1] : 0);
    if (i < Nn) off[i] = cb + incl - v;
    __syncthreads();
    if (tid == 1023) carry = cb + incl;
    __syncthreads();
  }
  if (tid == 0) off[Nn] = carry;
}

__global__ void scatter_kernel(const int* __restrict__ src, const int* __restrict__ dst,
                               const int* __restrict__ off, int* __restrict__ cur,
                               int* __restrict__ ssrc) {
  int i = blockIdx.x * blockDim.x + threadIdx.x;
  int stride = gridDim.x * blockDim.x;
  for (; i < Ee; i += stride) {
    int d = dst[i];
    int pos = off[d] + atomicAdd(&cur[d], 1);
    ssrc[pos] = src[i];
  }
}

// ---------------- fp32 -> split bf16 conversions ----------------

// in [M][K] fp32 -> out [M][2K] bf16: cols [0,K)=hi, [K,2K)=lo
__global__ void split_kernel(const float* __restrict__ in, unsigned short* __restrict__ out,
                             int M, int K) {
  const int kg4 = K >> 2;
  int i = blockIdx.x * blockDim.x + threadIdx.x;
  const int total = M * kg4;
  const int stride = gridDim.x * blockDim.x;
  for (; i < total; i += stride) {
    const int row = i / kg4, kg = i - row * kg4;
    const float4 v = *(const float4*)(in + (size_t)row * K + kg * 4);
    ushort4 h, l;
    h.x = f2bf(v.x); l.x = f2bf(v.x - bf2f(h.x));
    h.y = f2bf(v.y); l.y = f2bf(v.y - bf2f(h.y));
    h.z = f2bf(v.z); l.z = f2bf(v.z - bf2f(h.z));
    h.w = f2bf(v.w); l.w = f2bf(v.w - bf2f(h.w));
    *(ushort4*)(out + (size_t)row * 2 * K + kg * 4) = h;
    *(ushort4*)(out + (size_t)row * 2 * K + K + kg * 4) = l;
  }
}

// 4x W [K][256] fp32 -> B3T [1024][3K] bf16 (transposed): cols [0,K)=hi, [K,2K)=hi, [2K,3K)=lo
__global__ void convw_kernel(const float* __restrict__ W0, const float* __restrict__ W1,
                             const float* __restrict__ W2, const float* __restrict__ W3,
                             unsigned short* __restrict__ B3, int K) {
  int i = blockIdx.x * blockDim.x + threadIdx.x;
  const int total = 1024 * K;
  const int stride = gridDim.x * blockDim.x;
  for (; i < total; i += stride) {
    const int n = i & 1023;
    const int k = i >> 10;
    const int z = n >> 8, c = n & 255;
    const float* W = z == 0 ? W0 : z == 1 ? W1 : z == 2 ? W2 : W3;
    const float v = W[(size_t)k * Dd + c];
    const unsigned short h = f2bf(v);
    const unsigned short l = f2bf(v - bf2f(h));
    unsigned short* row = B3 + (size_t)n * 3 * K;
    row[k] = h; row[K + k] = h; row[2 * K + k] = l;
  }
}

// ---------------- split-bf16 MFMA GEMM: C[z][M][256] = A @ [Wq|Wk|Wv|Ws] + b ----------------
// A3 [M][2K] bf16 (hi|lo), B3 [1024][3K] bf16 (hi|hi|lo).
// term sum: hi_a*hi_b + lo_a*hi_b + hi_a*lo_b  (~fp32 accuracy)

__global__ __launch_bounds__(256)
void gemm_mfma(const unsigned short* __restrict__ A3, int M, int K,
               const unsigned short* __restrict__ B3,
               const float* __restrict__ b0, const float* __restrict__ b1,
               const float* __restrict__ b2, const float* __restrict__ b3,
               float* __restrict__ C) {
  __shared__ __align__(16) unsigned short As[128 * 64];
  __shared__ __align__(16) unsigned short Bs[128 * 64];
  const int tid = threadIdx.x;
  const int lane = tid & 63, w = tid >> 6;
  const int wr = w >> 1, wc = w & 1;
  const int bm = blockIdx.x * 128, bn = blockIdx.y * 128;
  const int lda = 2 * K, ldb = 3 * K;
  const int nsA = (2 * K) >> 6;
  const int nsteps = (3 * K) >> 6;
  const int srow = lane >> 3, sslot = lane & 7;
  const int fr = lane & 15, fq = lane >> 4;

  f32x4 acc[4][4] = {};

  for (int s = 0; s < nsteps; ++s) {
    const int ak = (s < nsA ? s : s - nsA) << 6;
    const int bk = s << 6;
    __syncthreads();
    // stage 128x64 bf16 tiles; LDS rows 128B, slot s holds global col-group (s ^ (row&7))
#pragma unroll
    for (int h = 0; h < 4; ++h) {
      const int q = h * 4 + w;          // 1KB chunk index, wave-uniform
      const int r = q * 8 + srow;       // tile row
      const int g = sslot ^ (r & 7);    // pre-swizzled global col-group
      int ga = bm + r; if (ga > M - 1) ga = M - 1;
      gload16(A3 + (size_t)ga * lda + ak + g * 8, (char*)As + q * 1024);
      const int gb = bn + r;
      gload16(B3 + (size_t)gb * ldb + bk + g * 8, (char*)Bs + q * 1024);
    }
    __syncthreads();
    short8 av[2][4], bv[2][4];
#pragma unroll
    for (int kh = 0; kh < 2; ++kh)
#pragma unroll
      for (int i = 0; i < 4; ++i) {
        const int ra = wr * 64 + i * 16 + fr;
        av[kh][i] = *(const short8*)((const char*)As + ra * 128 + (((kh * 4 + fq) ^ (ra & 7)) << 4));
        const int rb = wc * 64 + i * 16 + fr;
        bv[kh][i] = *(const short8*)((const char*)Bs + rb * 128 + (((kh * 4 + fq) ^ (rb & 7)) << 4));
      }
#pragma unroll
    for (int kh = 0; kh < 2; ++kh)
#pragma unroll
      for (int mi = 0; mi < 4; ++mi)
#pragma unroll
        for (int ni = 0; ni < 4; ++ni)
          acc[mi][ni] = __builtin_amdgcn_mfma_f32_16x16x32_bf16(
              __builtin_bit_cast(bf16x8, av[kh][mi]),
              __builtin_bit_cast(bf16x8, bv[kh][ni]), acc[mi][ni], 0, 0, 0);
  }

  // epilogue: C/D layout col=lane&15, row=(lane>>4)*4+j (m89-verified)
#pragma unroll
  for (int mi = 0; mi < 4; ++mi) {
    const int grow0 = bm + wr * 64 + mi * 16 + fq * 4;
#pragma unroll
    for (int ni = 0; ni < 4; ++ni) {
      const int nbase = bn + wc * 64 + ni * 16;
      const int z = nbase >> 8;
      const int c = (nbase & 255) + fr;
      const float* bp = z == 0 ? b0 : z == 1 ? b1 : z == 2 ? b2 : b3;
      const float bias = bp[c];
      float* Cz = C + (size_t)z * M * Dd;
#pragma unroll
      for (int j = 0; j < 4; ++j) {
        const int grow = grow0 + j;
        if (grow < M) Cz[(size_t)grow * Dd + c] = acc[mi][ni][j] + bias;
      }
    }
  }
}

// ---------------- per-node attention (one wave per dst node, online softmax) ----------------
// MODE 0: write relu(out) as split bf16 [Nn][512] (hi|lo) for next GEMM
// MODE 1: write relu(out) as fp32 [Nn][256]

template <int MODE>
__global__ __launch_bounds__(256)
void attn_kernel(const float* __restrict__ qkvs, const int* __restrict__ off,
                 const int* __restrict__ ssrc, float* __restrict__ hout,
                 unsigned short* __restrict__ h3out) {
  int gw = (int)((blockIdx.x * 256 + threadIdx.x) >> 6);
  if (gw >= Nn) return;
  int lane = threadIdx.x & 63;
  const float* Kbase = qkvs + (size_t)Nn * Dd;
  const float* Vbase = Kbase + (size_t)Nn * Dd;
  const float* Sbase = Vbase + (size_t)Nn * Dd;

  float4 q = *(const float4*)(qkvs + (size_t)gw * Dd + lane * 4);
  int e0 = off[gw], e1 = off[gw + 1];
  const float scale = 0.08838834764831845f;

  float m = -3.4e38f, d = 0.f;
  float ax = 0.f, ay = 0.f, az = 0.f, aw = 0.f;

  for (int e = e0; e < e1; ++e) {
    int s = ssrc[e];
    float4 kv = *(const float4*)(Kbase + (size_t)s * Dd + lane * 4);
    float4 vv = *(const float4*)(Vbase + (size_t)s * Dd + lane * 4);
    float p = q.x * kv.x + q.y * kv.y + q.z * kv.z + q.w * kv.w;
    p += __shfl_xor(p, 16);
    p += __shfl_xor(p, 8);
    p += __shfl_xor(p, 4);
    p += __shfl_xor(p, 2);
    p += __shfl_xor(p, 1);
    float sc = p * scale;
    float nm = fmaxf(m, sc);
    float f = __expf(m - nm);
    float wgt = __expf(sc - nm);
    d = d * f + wgt;
    ax = ax * f + wgt * vv.x;
    ay = ay * f + wgt * vv.y;
    az = az * f + wgt * vv.z;
    aw = aw * f + wgt * vv.w;
    m = nm;
  }
  float inv = 1.f / (d + 1e-16f);
  float4 sk = *(const float4*)(Sbase + (size_t)gw * Dd + lane * 4);
  float4 o;
  o.x = fmaxf(ax * inv + sk.x, 0.f);
  o.y = fmaxf(ay * inv + sk.y, 0.f);
  o.z = fmaxf(az * inv + sk.z, 0.f);
  o.w = fmaxf(aw * inv + sk.w, 0.f);
  if (MODE == 0) {
    ushort4 hh, ll;
    hh.x = f2bf(o.x); ll.x = f2bf(o.x - bf2f(hh.x));
    hh.y = f2bf(o.y); ll.y = f2bf(o.y - bf2f(hh.y));
    hh.z = f2bf(o.z); ll.z = f2bf(o.z - bf2f(hh.z));
    hh.w = f2bf(o.w); ll.w = f2bf(o.w - bf2f(hh.w));
    *(ushort4*)(h3out + (size_t)gw * 512 + lane * 4) = hh;
    *(ushort4*)(h3out + (size_t)gw * 512 + 256 + lane * 4) = ll;
  } else {
    *(float4*)(hout + (size_t)gw * Dd + lane * 4) = o;
  }
}

// ---------------- pooling + fc ----------------

__global__ __launch_bounds__(256)
void pool_kernel(const float* __restrict__ h, const int* __restrict__ batch,
                 float* __restrict__ pooled) {
  int c = threadIdx.x;
  int n0 = blockIdx.x * 128;
  int n1 = min(n0 + 128, Nn);
  int curg = batch[n0];
  float mx = 0.f;
  for (int n = n0; n < n1; ++n) {
    int g = batch[n];
    if (g != curg) {
      atomicMax((int*)(pooled + curg * Dd + c), __float_as_int(mx));
      mx = 0.f;
      curg = g;
    }
    mx = fmaxf(mx, h[(size_t)n * Dd + c]);
  }
  atomicMax((int*)(pooled + curg * Dd + c), __float_as_int(mx));
}

__global__ __launch_bounds__(512)
void fc_kernel(const float* __restrict__ pooled,
               const float* __restrict__ wf1, const float* __restrict__ bf1,
               const float* __restrict__ wf2, const float* __restrict__ bf2,
               float* __restrict__ outp) {
  __shared__ float t[Gg][64];
  int tid = threadIdx.x;
  int g = tid >> 6, j = tid & 63;
  float acc = bf1[j];
  for (int c = 0; c < Dd; ++c) acc = fmaf(pooled[g * Dd + c], wf1[c * 64 + j], acc);
  t[g][j] = acc;
  __syncthreads();
  if (tid < Gg * 4) {
    int gg = tid >> 2, cc = tid & 3;
    float a2 = bf2[cc];
    for (int j2 = 0; j2 < 64; ++j2) a2 = fmaf(t[gg][j2], wf2[j2 * 4 + cc], a2);
    outp[gg * 4 + cc] = a2;
  }
}

// ---------------- host ----------------

extern "C" void kernel_launch(void* const* d_in, const int* in_sizes, int n_in,
                              void* d_out, int out_size, void* d_ws, size_t ws_size,
                              hipStream_t stream) {
  const float* x   = (const float*)d_in[0];
  const int* ei    = (const int*)d_in[1];
  const int* srcE  = ei;
  const int* dstE  = ei + Ee;
  const int* batch = (const int*)d_in[2];
  const float* wq1 = (const float*)d_in[3];  const float* bq1 = (const float*)d_in[4];
  const float* wk1 = (const float*)d_in[5];  const float* bk1 = (const float*)d_in[6];
  const float* wv1 = (const float*)d_in[7];  const float* bv1 = (const float*)d_in[8];
  const float* ws1 = (const float*)d_in[9];  const float* bs1 = (const float*)d_in[10];
  const float* wq2 = (const float*)d_in[11]; const float* bq2 = (const float*)d_in[12];
  const float* wk2 = (const float*)d_in[13]; const float* bk2 = (const float*)d_in[14];
  const float* wv2 = (const float*)d_in[15]; const float* bv2 = (const float*)d_in[16];
  const float* ws2 = (const float*)d_in[17]; const float* bs2 = (const float*)d_in[18];
  const float* wf1 = (const float*)d_in[19]; const float* bf1 = (const float*)d_in[20];
  const float* wf2 = (const float*)d_in[21]; const float* bf2 = (const float*)d_in[22];
  float* outp = (float*)d_out;
  char* ws = (char*)d_ws;

  auto al256 = [](size_t v) { return (v + 255) & ~(size_t)255; };
  size_t o_deg  = 0;
  size_t o_cur  = o_deg + (size_t)Nn * 4;
  size_t o_pool = o_cur + (size_t)Nn * 4;
  size_t zbytes = o_pool + (size_t)Gg * Dd * 4;
  size_t o_off  = al256(zbytes);
  size_t o_ssrc = al256(o_off + (size_t)(Nn + 1) * 4);
  size_t o_qkvs = al256(o_ssrc + (size_t)Ee * 4);
  size_t o_b31  = al256(o_qkvs + (size_t)4 * Nn * Dd * 4);
  size_t o_b32  = al256(o_b31 + (size_t)1024 * 3 * Ff * 2);
  size_t o_big  = al256(o_b32 + (size_t)1024 * 3 * Dd * 2);
  size_t big_sz = (size_t)Nn * 2 * Ff * 2;                 // A3_1: 102.4MB
  size_t total  = o_big + big_sz;
  if (ws_size < total) {
    fprintf(stderr, "kernel_launch: ws too small: %zu < %zu\n", ws_size, total);
    return;
  }

  int*   deg    = (int*)(ws + o_deg);
  int*   cur    = (int*)(ws + o_cur);
  float* pooled = (float*)(ws + o_pool);
  int*   off    = (int*)(ws + o_off);
  int*   ssrc   = (int*)(ws + o_ssrc);
  float* qkvs   = (float*)(ws + o_qkvs);
  unsigned short* b31 = (unsigned short*)(ws + o_b31);
  unsigned short* b32 = (unsigned short*)(ws + o_b32);
  unsigned short* a31 = (unsigned short*)(ws + o_big);                       // [Nn][1024]
  unsigned short* h3  = (unsigned short*)(ws + o_big);                       // [Nn][512] overlays a31
  float* h2     = (float*)(ws + o_big + (size_t)Nn * 512 * 2);               // [Nn][256]

  hipMemsetAsync(ws, 0, zbytes, stream);
  hist_kernel<<<1024, 256, 0, stream>>>(dstE, deg);
  scan_kernel<<<1, 1024, 0, stream>>>(deg, off);
  scatter_kernel<<<1024, 256, 0, stream>>>(srcE, dstE, off, cur, ssrc);

  convw_kernel<<<1024, 256, 0, stream>>>(wq1, wk1, wv1, ws1, b31, Ff);
  convw_kernel<<<1024, 256, 0, stream>>>(wq2, wk2, wv2, ws2, b32, Dd);
  split_kernel<<<4096, 256, 0, stream>>>(x, a31, Nn, Ff);

  dim3 ggrid((Nn + 127) / 128, 8);
  gemm_mfma<<<ggrid, 256, 0, stream>>>(a31, Nn, Ff, b31, bq1, bk1, bv1, bs1, qkvs);
  attn_kernel<0><<<(Nn + 3) / 4, 256, 0, stream>>>(qkvs, off, ssrc, nullptr, h3);
  gemm_mfma<<<ggrid, 256, 0, stream>>>(h3, Nn, Dd, b32, bq2, bk2, bv2, bs2, qkvs);
  attn_kernel<1><<<(Nn + 3) / 4, 256, 0, stream>>>(qkvs, off, ssrc, h2, nullptr);

  pool_kernel<<<(Nn + 127) / 128, 256, 0, stream>>>(h2, batch, pooled);
  fc_kernel<<<1, 512, 0, stream>>>(pooled, wf1, bf1, wf2, bf2, outp);
}

// Round 3
// 828.712 us; speedup vs baseline: 1.9039x; 1.3328x over previous
//
#include <hip/hip_runtime.h>
#include <cstdio>

#define Nn 50000
#define Ee 800000
#define Ff 512
#define Dd 256
#define Gg 8

typedef short short8 __attribute__((ext_vector_type(8)));
typedef unsigned short ushort8v __attribute__((ext_vector_type(8)));
typedef __bf16 bf16x8 __attribute__((ext_vector_type(8)));
typedef float f32x4 __attribute__((ext_vector_type(4)));

__device__ inline unsigned short f2bf(float f) {
  unsigned u = __float_as_uint(f);
  u += 0x7FFFu + ((u >> 16) & 1u);
  return (unsigned short)(u >> 16);
}
__device__ inline float bf2f(unsigned short h) {
  return __uint_as_float(((unsigned)h) << 16);
}

__device__ inline void gload16(const void* g, void* l) {
  __builtin_amdgcn_global_load_lds((const __attribute__((address_space(1))) void*)g,
                                   (__attribute__((address_space(3))) void*)l, 16, 0, 0);
}

// ---------------- CSR build ----------------

__global__ void hist_kernel(const int* __restrict__ dst, int* __restrict__ deg) {
  int i = blockIdx.x * blockDim.x + threadIdx.x;
  int stride = gridDim.x * blockDim.x;
  for (; i < Ee; i += stride) atomicAdd(&deg[dst[i]], 1);
}

__global__ __launch_bounds__(1024) void scan_kernel(const int* __restrict__ deg, int* __restrict__ off) {
  __shared__ int wsum[16];
  __shared__ int carry;
  int tid = threadIdx.x;
  int lane = tid & 63, w = tid >> 6;
  if (tid == 0) carry = 0;
  __syncthreads();
  for (int start = 0; start < Nn; start += 1024) {
    int i = start + tid;
    int v = (i < Nn) ? deg[i] : 0;
    int x = v;
#pragma unroll
    for (int o = 1; o < 64; o <<= 1) {
      int t = __shfl_up(x, o);
      if (lane >= o) x += t;
    }
    if (lane == 63) wsum[w] = x;
    __syncthreads();
    if (w == 0 && lane < 16) {
      int y = wsum[lane];
#pragma unroll
      for (int o = 1; o < 16; o <<= 1) {
        int t = __shfl_up(y, o);
        if (lane >= o) y += t;
      }
      wsum[lane] = y;
    }
    __syncthreads();
    int cb = carry;
    int incl = x + (w ? wsum[w - 1] : 0);
    if (i < Nn) off[i] = cb + incl - v;
    __syncthreads();
    if (tid == 1023) carry = cb + incl;
    __syncthreads();
  }
  if (tid == 0) off[Nn] = carry;
}

__global__ void scatter_kernel(const int* __restrict__ src, const int* __restrict__ dst,
                               const int* __restrict__ off, int* __restrict__ cur,
                               int* __restrict__ ssrc) {
  int i = blockIdx.x * blockDim.x + threadIdx.x;
  int stride = gridDim.x * blockDim.x;
  for (; i < Ee; i += stride) {
    int d = dst[i];
    int pos = off[d] + atomicAdd(&cur[d], 1);
    ssrc[pos] = src[i];
  }
}

// ---------------- fp32 -> split bf16 conversions ----------------

__global__ void split_kernel(const float* __restrict__ in, unsigned short* __restrict__ out,
                             int M, int K) {
  const int kg4 = K >> 2;
  int i = blockIdx.x * blockDim.x + threadIdx.x;
  const int total = M * kg4;
  const int stride = gridDim.x * blockDim.x;
  for (; i < total; i += stride) {
    const int row = i / kg4, kg = i - row * kg4;
    const float4 v = *(const float4*)(in + (size_t)row * K + kg * 4);
    ushort4 h, l;
    h.x = f2bf(v.x); l.x = f2bf(v.x - bf2f(h.x));
    h.y = f2bf(v.y); l.y = f2bf(v.y - bf2f(h.y));
    h.z = f2bf(v.z); l.z = f2bf(v.z - bf2f(h.z));
    h.w = f2bf(v.w); l.w = f2bf(v.w - bf2f(h.w));
    *(ushort4*)(out + (size_t)row * 2 * K + kg * 4) = h;
    *(ushort4*)(out + (size_t)row * 2 * K + K + kg * 4) = l;
  }
}

__global__ void convw_kernel(const float* __restrict__ W0, const float* __restrict__ W1,
                             const float* __restrict__ W2, const float* __restrict__ W3,
                             unsigned short* __restrict__ B3, int K) {
  int i = blockIdx.x * blockDim.x + threadIdx.x;
  const int total = 1024 * K;
  const int stride = gridDim.x * blockDim.x;
  for (; i < total; i += stride) {
    const int n = i & 1023;
    const int k = i >> 10;
    const int z = n >> 8, c = n & 255;
    const float* W = z == 0 ? W0 : z == 1 ? W1 : z == 2 ? W2 : W3;
    const float v = W[(size_t)k * Dd + c];
    const unsigned short h = f2bf(v);
    const unsigned short l = f2bf(v - bf2f(h));
    unsigned short* row = B3 + (size_t)n * 3 * K;
    row[k] = h; row[K + k] = h; row[2 * K + k] = l;
  }
}

// ---------------- split-bf16 MFMA GEMM, XCD-swizzled grid ----------------
// outputs: z=0 -> q fp32 [M][256]; z=1/2 -> kv bf16 [M][512] interleaved
// (channel c: K at (c>>2)*8+(c&3), V at +4); z=3 -> s fp32 [M][256]

__global__ __launch_bounds__(256)
void gemm_mfma(const unsigned short* __restrict__ A3, int M, int K,
               const unsigned short* __restrict__ B3,
               const float* __restrict__ b0, const float* __restrict__ b1,
               const float* __restrict__ b2, const float* __restrict__ b3,
               float* __restrict__ qout, unsigned short* __restrict__ kvout,
               float* __restrict__ sout) {
  __shared__ __align__(16) unsigned short As[128 * 64];
  __shared__ __align__(16) unsigned short Bs[128 * 64];
  const int tid = threadIdx.x;
  const int lane = tid & 63, w = tid >> 6;
  const int wr = w >> 1, wc = w & 1;
  // XCD-aware swizzle: 3136 blocks, xcd p&7 owns 49 contiguous row-tiles,
  // its 8 column-groups of a row-tile adjacent in time -> A panel L2-resident
  const int p = blockIdx.x;
  const int xcd = p & 7;
  const int i2 = p >> 3;
  const int bm = (xcd * 49 + (i2 >> 3)) * 128;
  const int bn = (i2 & 7) * 128;
  const int lda = 2 * K, ldb = 3 * K;
  const int nsA = (2 * K) >> 6;
  const int nsteps = (3 * K) >> 6;
  const int srow = lane >> 3, sslot = lane & 7;
  const int fr = lane & 15, fq = lane >> 4;

  f32x4 acc[4][4] = {};

  for (int s = 0; s < nsteps; ++s) {
    const int ak = (s < nsA ? s : s - nsA) << 6;
    const int bk = s << 6;
    __syncthreads();
#pragma unroll
    for (int h = 0; h < 4; ++h) {
      const int q = h * 4 + w;
      const int r = q * 8 + srow;
      const int g = sslot ^ (r & 7);
      int ga = bm + r; if (ga > M - 1) ga = M - 1;
      gload16(A3 + (size_t)ga * lda + ak + g * 8, (char*)As + q * 1024);
      const int gb = bn + r;
      gload16(B3 + (size_t)gb * ldb + bk + g * 8, (char*)Bs + q * 1024);
    }
    __syncthreads();
    short8 av[2][4], bv[2][4];
#pragma unroll
    for (int kh = 0; kh < 2; ++kh)
#pragma unroll
      for (int i = 0; i < 4; ++i) {
        const int ra = wr * 64 + i * 16 + fr;
        av[kh][i] = *(const short8*)((const char*)As + ra * 128 + (((kh * 4 + fq) ^ (ra & 7)) << 4));
        const int rb = wc * 64 + i * 16 + fr;
        bv[kh][i] = *(const short8*)((const char*)Bs + rb * 128 + (((kh * 4 + fq) ^ (rb & 7)) << 4));
      }
#pragma unroll
    for (int kh = 0; kh < 2; ++kh)
#pragma unroll
      for (int mi = 0; mi < 4; ++mi)
#pragma unroll
        for (int ni = 0; ni < 4; ++ni)
          acc[mi][ni] = __builtin_amdgcn_mfma_f32_16x16x32_bf16(
              __builtin_bit_cast(bf16x8, av[kh][mi]),
              __builtin_bit_cast(bf16x8, bv[kh][ni]), acc[mi][ni], 0, 0, 0);
  }

#pragma unroll
  for (int mi = 0; mi < 4; ++mi) {
    const int grow0 = bm + wr * 64 + mi * 16 + fq * 4;
#pragma unroll
    for (int ni = 0; ni < 4; ++ni) {
      const int nbase = bn + wc * 64 + ni * 16;
      const int z = nbase >> 8;
      const int c = (nbase & 255) + fr;
      const float* bp = z == 0 ? b0 : z == 1 ? b1 : z == 2 ? b2 : b3;
      const float bias = bp[c];
#pragma unroll
      for (int j = 0; j < 4; ++j) {
        const int grow = grow0 + j;
        if (grow < M) {
          const float val = acc[mi][ni][j] + bias;
          if (z == 0) {
            qout[(size_t)grow * Dd + c] = val;
          } else if (z == 3) {
            sout[(size_t)grow * Dd + c] = val;
          } else {
            const int idx = ((c >> 2) << 3) + (c & 3) + (z == 2 ? 4 : 0);
            kvout[(size_t)grow * 512 + idx] = f2bf(val);
          }
        }
      }
    }
  }
}

// ---------------- per-node attention (one wave per dst node, online softmax) ----------------
// kv: bf16 [Nn][512], lane's 16B slot = {K[4c..4c+3], V[4c..4c+3]}
// MODE 0: write relu(out) split bf16 [Nn][512]; MODE 1: fp32 [Nn][256]

template <int MODE>
__global__ __launch_bounds__(256)
void attn_kernel(const float* __restrict__ qbuf, const unsigned short* __restrict__ kvbuf,
                 const float* __restrict__ sbuf, const int* __restrict__ off,
                 const int* __restrict__ ssrc, float* __restrict__ hout,
                 unsigned short* __restrict__ h3out) {
  int gw = (int)((blockIdx.x * 256 + threadIdx.x) >> 6);
  if (gw >= Nn) return;
  int lane = threadIdx.x & 63;

  float4 q = *(const float4*)(qbuf + (size_t)gw * Dd + lane * 4);
  int e0 = off[gw], e1 = off[gw + 1];
  const float scale = 0.08838834764831845f;

  float m = -3.4e38f, d = 0.f;
  float ax = 0.f, ay = 0.f, az = 0.f, aw = 0.f;

  int e = e0;
  for (; e + 2 <= e1; e += 2) {
    int s0 = ssrc[e], s1 = ssrc[e + 1];
    ushort8v u0 = *(const ushort8v*)(kvbuf + (size_t)s0 * 512 + lane * 8);
    ushort8v u1 = *(const ushort8v*)(kvbuf + (size_t)s1 * 512 + lane * 8);
    float p0 = q.x * bf2f(u0[0]);  p0 = fmaf(q.y, bf2f(u0[1]), p0);
    p0 = fmaf(q.z, bf2f(u0[2]), p0); p0 = fmaf(q.w, bf2f(u0[3]), p0);
    float p1 = q.x * bf2f(u1[0]);  p1 = fmaf(q.y, bf2f(u1[1]), p1);
    p1 = fmaf(q.z, bf2f(u1[2]), p1); p1 = fmaf(q.w, bf2f(u1[3]), p1);
    p0 += __shfl_xor(p0, 16); p1 += __shfl_xor(p1, 16);
    p0 += __shfl_xor(p0, 8);  p1 += __shfl_xor(p1, 8);
    p0 += __shfl_xor(p0, 4);  p1 += __shfl_xor(p1, 4);
    p0 += __shfl_xor(p0, 2);  p1 += __shfl_xor(p1, 2);
    p0 += __shfl_xor(p0, 1);  p1 += __shfl_xor(p1, 1);
    float sc0 = p0 * scale, sc1 = p1 * scale;
    float nm = fmaxf(m, fmaxf(sc0, sc1));
    float f = __expf(m - nm);
    float w0 = __expf(sc0 - nm), w1 = __expf(sc1 - nm);
    d = d * f + w0 + w1;
    ax = ax * f + w0 * bf2f(u0[4]) + w1 * bf2f(u1[4]);
    ay = ay * f + w0 * bf2f(u0[5]) + w1 * bf2f(u1[5]);
    az = az * f + w0 * bf2f(u0[6]) + w1 * bf2f(u1[6]);
    aw = aw * f + w0 * bf2f(u0[7]) + w1 * bf2f(u1[7]);
    m = nm;
  }
  if (e < e1) {
    int s0 = ssrc[e];
    ushort8v u0 = *(const ushort8v*)(kvbuf + (size_t)s0 * 512 + lane * 8);
    float p0 = q.x * bf2f(u0[0]);  p0 = fmaf(q.y, bf2f(u0[1]), p0);
    p0 = fmaf(q.z, bf2f(u0[2]), p0); p0 = fmaf(q.w, bf2f(u0[3]), p0);
    p0 += __shfl_xor(p0, 16);
    p0 += __shfl_xor(p0, 8);
    p0 += __shfl_xor(p0, 4);
    p0 += __shfl_xor(p0, 2);
    p0 += __shfl_xor(p0, 1);
    float sc0 = p0 * scale;
    float nm = fmaxf(m, sc0);
    float f = __expf(m - nm);
    float w0 = __expf(sc0 - nm);
    d = d * f + w0;
    ax = ax * f + w0 * bf2f(u0[4]);
    ay = ay * f + w0 * bf2f(u0[5]);
    az = az * f + w0 * bf2f(u0[6]);
    aw = aw * f + w0 * bf2f(u0[7]);
    m = nm;
  }

  float inv = 1.f / (d + 1e-16f);
  float4 sk = *(const float4*)(sbuf + (size_t)gw * Dd + lane * 4);
  float4 o;
  o.x = fmaxf(ax * inv + sk.x, 0.f);
  o.y = fmaxf(ay * inv + sk.y, 0.f);
  o.z = fmaxf(az * inv + sk.z, 0.f);
  o.w = fmaxf(aw * inv + sk.w, 0.f);
  if (MODE == 0) {
    ushort4 hh, ll;
    hh.x = f2bf(o.x); ll.x = f2bf(o.x - bf2f(hh.x));
    hh.y = f2bf(o.y); ll.y = f2bf(o.y - bf2f(hh.y));
    hh.z = f2bf(o.z); ll.z = f2bf(o.z - bf2f(hh.z));
    hh.w = f2bf(o.w); ll.w = f2bf(o.w - bf2f(hh.w));
    *(ushort4*)(h3out + (size_t)gw * 512 + lane * 4) = hh;
    *(ushort4*)(h3out + (size_t)gw * 512 + 256 + lane * 4) = ll;
  } else {
    *(float4*)(hout + (size_t)gw * Dd + lane * 4) = o;
  }
}

// ---------------- pooling + fc ----------------

__global__ __launch_bounds__(256)
void pool_kernel(const float* __restrict__ h, const int* __restrict__ batch,
                 float* __restrict__ pooled) {
  int c = threadIdx.x;
  int n0 = blockIdx.x * 128;
  int n1 = min(n0 + 128, Nn);
  int curg = batch[n0];
  float mx = 0.f;
  for (int n = n0; n < n1; ++n) {
    int g = batch[n];
    if (g != curg) {
      atomicMax((int*)(pooled + curg * Dd + c), __float_as_int(mx));
      mx = 0.f;
      curg = g;
    }
    mx = fmaxf(mx, h[(size_t)n * Dd + c]);
  }
  atomicMax((int*)(pooled + curg * Dd + c), __float_as_int(mx));
}

__global__ __launch_bounds__(512)
void fc_kernel(const float* __restrict__ pooled,
               const float* __restrict__ wf1, const float* __restrict__ bf1,
               const float* __restrict__ wf2, const float* __restrict__ bf2,
               float* __restrict__ outp) {
  __shared__ float t[Gg][64];
  int tid = threadIdx.x;
  int g = tid >> 6, j = tid & 63;
  float acc = bf1[j];
  for (int c = 0; c < Dd; ++c) acc = fmaf(pooled[g * Dd + c], wf1[c * 64 + j], acc);
  t[g][j] = acc;
  __syncthreads();
  if (tid < Gg * 4) {
    int gg = tid >> 2, cc = tid & 3;
    float a2 = bf2[cc];
    for (int j2 = 0; j2 < 64; ++j2) a2 = fmaf(t[gg][j2], wf2[j2 * 4 + cc], a2);
    outp[gg * 4 + cc] = a2;
  }
}

// ---------------- host ----------------

extern "C" void kernel_launch(void* const* d_in, const int* in_sizes, int n_in,
                              void* d_out, int out_size, void* d_ws, size_t ws_size,
                              hipStream_t stream) {
  const float* x   = (const float*)d_in[0];
  const int* ei    = (const int*)d_in[1];
  const int* srcE  = ei;
  const int* dstE  = ei + Ee;
  const int* batch = (const int*)d_in[2];
  const float* wq1 = (const float*)d_in[3];  const float* bq1 = (const float*)d_in[4];
  const float* wk1 = (const float*)d_in[5];  const float* bk1 = (const float*)d_in[6];
  const float* wv1 = (const float*)d_in[7];  const float* bv1 = (const float*)d_in[8];
  const float* ws1 = (const float*)d_in[9];  const float* bs1 = (const float*)d_in[10];
  const float* wq2 = (const float*)d_in[11]; const float* bq2 = (const float*)d_in[12];
  const float* wk2 = (const float*)d_in[13]; const float* bk2 = (const float*)d_in[14];
  const float* wv2 = (const float*)d_in[15]; const float* bv2 = (const float*)d_in[16];
  const float* ws2 = (const float*)d_in[17]; const float* bs2 = (const float*)d_in[18];
  const float* wf1 = (const float*)d_in[19]; const float* bf1 = (const float*)d_in[20];
  const float* wf2 = (const float*)d_in[21]; const float* bf2 = (const float*)d_in[22];
  float* outp = (float*)d_out;
  char* ws = (char*)d_ws;

  auto al256 = [](size_t v) { return (v + 255) & ~(size_t)255; };
  size_t o_deg  = 0;
  size_t o_cur  = o_deg + (size_t)Nn * 4;
  size_t o_pool = o_cur + (size_t)Nn * 4;
  size_t zbytes = o_pool + (size_t)Gg * Dd * 4;
  size_t o_off  = al256(zbytes);
  size_t o_ssrc = al256(o_off + (size_t)(Nn + 1) * 4);
  size_t o_q    = al256(o_ssrc + (size_t)Ee * 4);
  size_t o_kv   = al256(o_q + (size_t)Nn * Dd * 4);
  size_t o_s    = al256(o_kv + (size_t)Nn * 512 * 2);
  size_t o_b31  = al256(o_s + (size_t)Nn * Dd * 4);
  size_t o_b32  = al256(o_b31 + (size_t)1024 * 3 * Ff * 2);
  size_t o_big  = al256(o_b32 + (size_t)1024 * 3 * Dd * 2);
  size_t big_sz = (size_t)Nn * 2 * Ff * 2;                 // A3_1: 102.4MB
  size_t total  = o_big + big_sz;
  if (ws_size < total) {
    fprintf(stderr, "kernel_launch: ws too small: %zu < %zu\n", ws_size, total);
    return;
  }

  int*   deg    = (int*)(ws + o_deg);
  int*   cur    = (int*)(ws + o_cur);
  float* pooled = (float*)(ws + o_pool);
  int*   off    = (int*)(ws + o_off);
  int*   ssrc   = (int*)(ws + o_ssrc);
  float* qb     = (float*)(ws + o_q);
  unsigned short* kvb = (unsigned short*)(ws + o_kv);
  float* sb     = (float*)(ws + o_s);
  unsigned short* b31 = (unsigned short*)(ws + o_b31);
  unsigned short* b32 = (unsigned short*)(ws + o_b32);
  unsigned short* a31 = (unsigned short*)(ws + o_big);                 // [Nn][1024]
  unsigned short* h3  = (unsigned short*)(ws + o_big);                 // [Nn][512] overlays a31
  float* h2     = (float*)(ws + o_big + (size_t)Nn * 512 * 2);         // [Nn][256]

  hipMemsetAsync(ws, 0, zbytes, stream);
  hist_kernel<<<1024, 256, 0, stream>>>(dstE, deg);
  scan_kernel<<<1, 1024, 0, stream>>>(deg, off);
  scatter_kernel<<<1024, 256, 0, stream>>>(srcE, dstE, off, cur, ssrc);

  convw_kernel<<<1024, 256, 0, stream>>>(wq1, wk1, wv1, ws1, b31, Ff);
  convw_kernel<<<1024, 256, 0, stream>>>(wq2, wk2, wv2, ws2, b32, Dd);
  split_kernel<<<4096, 256, 0, stream>>>(x, a31, Nn, Ff);

  gemm_mfma<<<3136, 256, 0, stream>>>(a31, Nn, Ff, b31, bq1, bk1, bv1, bs1, qb, kvb, sb);
  attn_kernel<0><<<(Nn + 3) / 4, 256, 0, stream>>>(qb, kvb, sb, off, ssrc, nullptr, h3);
  gemm_mfma<<<3136, 256, 0, stream>>>(h3, Nn, Dd, b32, bq2, bk2, bv2, bs2, qb, kvb, sb);
  attn_kernel<1><<<(Nn + 3) / 4, 256, 0, stream>>>(qb, kvb, sb, off, ssrc, h2, nullptr);

  pool_kernel<<<(Nn + 127) / 128, 256, 0, stream>>>(h2, batch, pooled);
  fc_kernel<<<1, 512, 0, stream>>>(pooled, wf1, bf1, wf2, bf2, outp);
}